// Round 2
// 11040.487 us; speedup vs baseline: 1.2185x; 1.2185x over previous
//
#include <hip/hip_runtime.h>

// GeodesicStateBlock: GRU-style scan (B=16,S=2048,D=512) + LayerNorm.
// Identity: deformed = points + (states - points) = states, so out = LN(states).
//
// Round-5 structure (revert of round-4's XCD election, which hung):
//  - Coherence model = round-3's proven one: all cross-block traffic uses
//    sc0 sc1 (LLC-coherent, placement-independent). Correctness never depends
//    on block->XCD assignment.
//  - Barrier: per-block FLAG ARRAY + parallel poll instead of one atomic
//    counter. Block j stores flag[j] = token (monotonic 2t+1 / 2t+2); wave 0
//    polls all 16 flags with ONE coalesced 64B load per iteration
//    (lane i reads flag[i&15], __all(v >= token)). Removes the 16-way
//    same-address atomic serialization and the atomic->spin dependent chain.
//  - LDS staging of h / rh fragments: the 4 waves cooperatively load 4
//    kc-fragments each (16KB per block instead of 4x16KB redundant), stage
//    into LDS in fragment order ([kc][lane] x 16B, conflict-free b128),
//    __syncthreads, then all waves read fragments from LDS. Cuts per-CU
//    LLC fabric traffic from 96KB/step to 32KB/step.
//  - xgt operands for step t+1 register-prefetched during phase B (in flight
//    across the barrier poll).

typedef _Float16 half8 __attribute__((ext_vector_type(8)));
typedef _Float16 half4 __attribute__((ext_vector_type(4)));
typedef float floatx4 __attribute__((ext_vector_type(4)));
typedef int int4v __attribute__((ext_vector_type(4)));

#define NBLK 16
#define TPB 256
#define S_LEN 2048

// ws layout (bytes)
#define SZ_WPK (96ull * 16 * 64 * 8 * 2)  // 1,572,864 (96 tiles x 16 KB)
#define OFF_WHPK 0ull
#define OFF_WXPK (OFF_WHPK + SZ_WPK)
#define OFF_HBUF (OFF_WXPK + SZ_WPK)   // 16 KB (zeroed: h0)
#define OFF_CNT (OFF_HBUF + 16384ull)  // 16 KB (zeroed: flags[0..15] used)
#define OFF_RH (OFF_CNT + 16384ull)    // 16 KB
#define OFF_XGT (OFF_RH + 16384ull)    // 2048*96*256*2 = 100,663,296 B

__device__ __forceinline__ float sigmoid_f(float x) {
  return 1.f / (1.f + __expf(-x));
}
__device__ __forceinline__ float tanh_f(float x) {
  x = fminf(15.f, fmaxf(-15.f, x));
  float e = __expf(2.f * x);
  return (e - 1.f) / (e + 1.f);
}

// ---- LLC-coherent (sc0 sc1) memory ops ----
// Load 4 A-fragments (16B each, 64B apart) + drain, in ONE asm block so the
// compiler can never schedule a use before the waitcnt.
__device__ __forceinline__ void ld4_cg(const _Float16* p, int4v (&f)[4]) {
  asm volatile(
      "global_load_dwordx4 %0, %4, off sc0 sc1\n\t"
      "global_load_dwordx4 %1, %4, off offset:64 sc0 sc1\n\t"
      "global_load_dwordx4 %2, %4, off offset:128 sc0 sc1\n\t"
      "global_load_dwordx4 %3, %4, off offset:192 sc0 sc1\n\t"
      "s_waitcnt vmcnt(0)"
      : "=&v"(f[0]), "=&v"(f[1]), "=&v"(f[2]), "=&v"(f[3])
      : "v"(p)
      : "memory");
}
__device__ __forceinline__ void st_cg_u16(_Float16* p, _Float16 v) {
  unsigned u = (unsigned)__builtin_bit_cast(unsigned short, v);
  asm volatile("global_store_short %0, %1, off sc0 sc1" ::"v"(p), "v"(u)
               : "memory");
}
__device__ __forceinline__ void vwait() {
  asm volatile("s_waitcnt vmcnt(0)" ::: "memory");
}
__device__ __forceinline__ void st_flag(unsigned* p, unsigned v) {
  asm volatile("global_store_dword %0, %1, off sc0 sc1" ::"v"(p), "v"(v)
               : "memory");
}
__device__ __forceinline__ unsigned ld_flag(const unsigned* p) {
  unsigned v;
  asm volatile("global_load_dword %0, %1, off sc0 sc1\n\t"
               "s_waitcnt vmcnt(0)"
               : "=v"(v)
               : "v"(p)
               : "memory");
  return v;
}

// Flag barrier: block j publishes token, wave 0 polls all 16 flags with one
// coalesced 64B load per iteration. Tokens are monotonic within a launch
// (2t+1 phase A, 2t+2 phase B); flags zeroed by memset each launch.
// Callers drain vmcnt for data stores BEFORE calling (store->flag ordering
// via LLC completion). Consecutive flag stores by a block are always
// separated by a vmcnt(0), so same-address store order is guaranteed.
__device__ __forceinline__ void gbar(unsigned* __restrict__ flags, int j,
                                     unsigned token, int wave, int lane) {
  __syncthreads();
  if (wave == 0) {
    if (lane == 0) st_flag(flags + j, token);
    const unsigned* fp = flags + (lane & 15);
    for (;;) {
      unsigned v = ld_flag(fp);
      if (__all((int)(v >= token))) break;
    }
  }
  __syncthreads();
}

// ---- pack weights into MFMA B-fragment order ----
// Whpk/Wxpk: [96 tiles][16 kc][64 lanes][8 f16]; tiles 0..63 gate, 64..95 cand.
// B-frag: lane holds B[k = kc*32 + (lane>>4)*8 + jj][n = lane&15].
__global__ void pack_kernel(const float* __restrict__ Wg,
                            const float* __restrict__ Wc,
                            _Float16* __restrict__ Whpk,
                            _Float16* __restrict__ Wxpk) {
  int unit = blockIdx.x * 4 + (threadIdx.x >> 6);  // 0..3071
  int lane = threadIdx.x & 63;
  int set = (unit >= 1536) ? 1 : 0;  // 0: h-part (rows 512+), 1: x-part
  int rem = unit - set * 1536;
  int tile = rem >> 4, kc = rem & 15;
  int kb = kc * 32 + ((lane >> 4) << 3);
  int n = lane & 15;
  int row0 = set ? 0 : 512;
  half8 w;
  if (tile < 64) {
    int col = tile * 16 + n;
#pragma unroll
    for (int jj = 0; jj < 8; ++jj)
      w[jj] = (_Float16)Wg[(size_t)(row0 + kb + jj) * 1024 + col];
  } else {
    int col = (tile - 64) * 16 + n;
#pragma unroll
    for (int jj = 0; jj < 8; ++jj)
      w[jj] = (_Float16)Wc[(size_t)(row0 + kb + jj) * 512 + col];
  }
  _Float16* dst = set ? Wxpk : Whpk;
  *(half8*)(dst + ((size_t)rem * 64 + lane) * 8) = w;
}

// ---- XGT = points @ W_x + bias, all steps; layout [t][tile][c16][b16] ----
__global__ __launch_bounds__(TPB) void xgemm_kernel(
    const float* __restrict__ points, const float* __restrict__ b_gate,
    const float* __restrict__ b_cand, const _Float16* __restrict__ Wxpk,
    _Float16* __restrict__ xgt) {
  __shared__ _Float16 x_lds[16][520];
  const int tid = threadIdx.x;
  const int wave = tid >> 6, lane = tid & 63;
  const int ln15 = lane & 15, q = lane >> 4;
  const int t = blockIdx.x;
  const int m = tid & 15, ch = tid >> 4;

  // stage x_t (f32 -> f16)
  const float* xp = points + ((size_t)m * S_LEN + t) * 512 + ch * 32;
#pragma unroll
  for (int u = 0; u < 4; ++u) {
    float4 f0 = ((const float4*)xp)[2 * u];
    float4 f1 = ((const float4*)xp)[2 * u + 1];
    half8 hv;
    hv[0] = (_Float16)f0.x; hv[1] = (_Float16)f0.y;
    hv[2] = (_Float16)f0.z; hv[3] = (_Float16)f0.w;
    hv[4] = (_Float16)f1.x; hv[5] = (_Float16)f1.y;
    hv[6] = (_Float16)f1.z; hv[7] = (_Float16)f1.w;
    *(half8*)&x_lds[m][ch * 32 + u * 8] = hv;
  }
  __syncthreads();

  for (int tile = wave; tile < 96; tile += 4) {
    const _Float16* W = Wxpk + (size_t)tile * 8192;
    floatx4 a0 = {0.f, 0.f, 0.f, 0.f}, a1 = {0.f, 0.f, 0.f, 0.f};
#pragma unroll
    for (int kc = 0; kc < 16; kc += 2) {
      a0 = __builtin_amdgcn_mfma_f32_16x16x32_f16(
          *(const half8*)&x_lds[ln15][kc * 32 + q * 8],
          *(const half8*)(W + ((size_t)kc * 64 + lane) * 8), a0, 0, 0, 0);
      a1 = __builtin_amdgcn_mfma_f32_16x16x32_f16(
          *(const half8*)&x_lds[ln15][(kc + 1) * 32 + q * 8],
          *(const half8*)(W + ((size_t)(kc + 1) * 64 + lane) * 8), a1, 0, 0, 0);
    }
    float bias = (tile < 64) ? b_gate[tile * 16 + ln15]
                             : b_cand[(tile - 64) * 16 + ln15];
    half4 o;
#pragma unroll
    for (int i = 0; i < 4; ++i) o[i] = (_Float16)(a0[i] + a1[i] + bias);
    *(half4*)(xgt + (((size_t)t * 96 + tile) * 16 + ln15) * 16 + q * 4) = o;
  }
}

// ---- serial recurrence: 16 persistent blocks, register-resident weights ----
__global__ __launch_bounds__(TPB, 1) void rec_kernel(
    const _Float16* __restrict__ Whpk, const _Float16* __restrict__ xgt,
    _Float16* __restrict__ h_buf, _Float16* __restrict__ rh_buf,
    unsigned* __restrict__ flags, float* __restrict__ out) {
  __shared__ int4v hsh[1024];  // 16KB: staged h / rh fragments [kc][lane]
  __shared__ float z_lds[16][36];

  const int tid = threadIdx.x;
  const int wave = tid >> 6, lane = tid & 63;
  const int ln15 = lane & 15, q = lane >> 4;
  const int j = blockIdx.x;

  // wave -> tiles: waves 0,1 gate-r tiles 2j,2j+1 (cols 32j..32j+31) + cand
  // tiles 64+2j,65+2j; waves 2,3 gate-z tiles 32+2j,33+2j.
  const int twA = (wave < 2) ? (2 * j + wave) : (32 + 2 * j + (wave - 2));
  const int twB = 64 + 2 * j + (wave & 1);
  const int colA = 32 * j + 16 * (wave & 1) + ln15;

  // weights -> registers (tile stride 8192 f16; kc stride 512 f16)
  half8 wA[16], wB[16];
  {
    const _Float16* sA = Whpk + (size_t)twA * 8192 + lane * 8;
#pragma unroll
    for (int kc = 0; kc < 16; ++kc) wA[kc] = *(const half8*)(sA + kc * 512);
  }
  if (wave < 2) {
    const _Float16* sB = Whpk + (size_t)twB * 8192 + lane * 8;
#pragma unroll
    for (int kc = 0; kc < 16; ++kc) wB[kc] = *(const half8*)(sB + kc * 512);
  }

  // cooperative staging base: wave w fetches kc = 4w..4w+3 for every lane.
  // A-frag (kc) byte addr = ln15*1024 + q*16 + kc*64  (= elements *2B).
  const _Float16* h_stage = h_buf + ln15 * 512 + q * 8 + wave * 128;
  const _Float16* rh_stage = rh_buf + ln15 * 512 + q * 8 + wave * 128;
  _Float16* rh_st = rh_buf + (q * 4) * 512 + colA;  // + i*512
  _Float16* h_st = h_buf + (q * 4) * 512 + colA;    // + i*512

  // xgt operand pointers; per-t stride = 96*16*16 = 24576 f16.
  const _Float16* xga_p = xgt + ((size_t)twA * 16 + ln15) * 16 + q * 4;
  const _Float16* xcb_p = xgt + ((size_t)twB * 16 + ln15) * 16 + q * 4;
  half4 xga = *(const half4*)xga_p;
  half4 xcb = {0, 0, 0, 0};
  if (wave < 2) xcb = *(const half4*)xcb_p;

  float hreg[4] = {0.f, 0.f, 0.f, 0.f};  // h[q*4+i][colA] (waves 0-1)

  for (int t = 0; t < S_LEN; ++t) {
    const size_t pn = (size_t)((t + 1 < S_LEN) ? t + 1 : t) * 24576;

    // ---- stage h fragments into LDS (16KB once per block, not 4x) ----
    {
      int4v f[4];
      ld4_cg(h_stage, f);
#pragma unroll
      for (int u = 0; u < 4; ++u) hsh[(4 * wave + u) * 64 + lane] = f[u];
    }
    __syncthreads();

    // phase A: gates = h @ Wg_h + xg
    floatx4 a0 = {0.f, 0.f, 0.f, 0.f}, a1 = {0.f, 0.f, 0.f, 0.f};
#pragma unroll
    for (int kc = 0; kc < 16; kc += 2) {
      a0 = __builtin_amdgcn_mfma_f32_16x16x32_f16(
          __builtin_bit_cast(half8, hsh[kc * 64 + lane]), wA[kc], a0, 0, 0, 0);
      a1 = __builtin_amdgcn_mfma_f32_16x16x32_f16(
          __builtin_bit_cast(half8, hsh[(kc + 1) * 64 + lane]), wA[kc + 1], a1,
          0, 0, 0);
    }
    if (wave < 2) {  // r-cols: publish r*h (LLC-coherent)
#pragma unroll
      for (int i = 0; i < 4; ++i) {
        float r = sigmoid_f(a0[i] + a1[i] + (float)xga[i]);
        st_cg_u16(rh_st + i * 512, (_Float16)(r * hreg[i]));
      }
      vwait();
    } else {  // z-cols: stash in LDS (consumed by waves 0-1 after the barrier)
#pragma unroll
      for (int i = 0; i < 4; ++i)
        z_lds[q * 4 + i][16 * (wave - 2) + ln15] =
            sigmoid_f(a0[i] + a1[i] + (float)xga[i]);
    }
    gbar(flags, j, 2u * t + 1u, wave, lane);

    // ---- stage rh fragments into LDS ----
    {
      int4v f[4];
      ld4_cg(rh_stage, f);
#pragma unroll
      for (int u = 0; u < 4; ++u) hsh[(4 * wave + u) * 64 + lane] = f[u];
    }
    __syncthreads();

    // phase B: cand = tanh(rh @ Wc_h + xc); h update; raw-state output
    if (wave < 2) {
      floatx4 b0 = {0.f, 0.f, 0.f, 0.f}, b1 = {0.f, 0.f, 0.f, 0.f};
#pragma unroll
      for (int kc = 0; kc < 16; kc += 2) {
        b0 = __builtin_amdgcn_mfma_f32_16x16x32_f16(
            __builtin_bit_cast(half8, hsh[kc * 64 + lane]), wB[kc], b0, 0, 0,
            0);
        b1 = __builtin_amdgcn_mfma_f32_16x16x32_f16(
            __builtin_bit_cast(half8, hsh[(kc + 1) * 64 + lane]), wB[kc + 1],
            b1, 0, 0, 0);
      }
      float hn_s[4];
#pragma unroll
      for (int i = 0; i < 4; ++i) {
        float cv = tanh_f(b0[i] + b1[i] + (float)xcb[i]);
        float zz = z_lds[q * 4 + i][16 * wave + ln15];
        float hn = hreg[i] + zz * (cv - hreg[i]);
        _Float16 hh = (_Float16)hn;
        hreg[i] = (float)hh;  // keep register copy == published f16 copy
        st_cg_u16(h_st + i * 512, hh);
        hn_s[i] = hn;
      }
      vwait();  // h stores drained before the barrier flag store
      // prefetch next step's xgt operands + out stores: in flight across the
      // barrier poll (poll's vmcnt(0) drains them during the wait).
      xga = *(const half4*)(xga_p + pn);
      xcb = *(const half4*)(xcb_p + pn);
#pragma unroll
      for (int i = 0; i < 4; ++i)
        out[((size_t)(q * 4 + i) * S_LEN + t) * 512 + colA] = hn_s[i];
    } else {
      xga = *(const half4*)(xga_p + pn);
    }
    gbar(flags, j, 2u * t + 2u, wave, lane);
  }
}

__global__ void ln_kernel(float* __restrict__ out, const float* __restrict__ gamma,
                          const float* __restrict__ beta) {
  int gw = (blockIdx.x * blockDim.x + threadIdx.x) >> 6;
  int lane = threadIdx.x & 63;
  int nw = (gridDim.x * blockDim.x) >> 6;
  float4 ga = ((const float4*)(gamma + lane * 8))[0];
  float4 gb = ((const float4*)(gamma + lane * 8))[1];
  float4 ba = ((const float4*)(beta + lane * 8))[0];
  float4 bb = ((const float4*)(beta + lane * 8))[1];
  for (int r = gw; r < 16 * S_LEN; r += nw) {
    float* p = out + (size_t)r * 512 + lane * 8;
    float4 v0 = ((float4*)p)[0], v1 = ((float4*)p)[1];
    float s = v0.x + v0.y + v0.z + v0.w + v1.x + v1.y + v1.z + v1.w;
    float sq = v0.x * v0.x + v0.y * v0.y + v0.z * v0.z + v0.w * v0.w +
               v1.x * v1.x + v1.y * v1.y + v1.z * v1.z + v1.w * v1.w;
#pragma unroll
    for (int off = 32; off > 0; off >>= 1) {
      s += __shfl_xor(s, off);
      sq += __shfl_xor(sq, off);
    }
    float mean = s * (1.f / 512.f);
    float var = sq * (1.f / 512.f) - mean * mean;
    float rstd = rsqrtf(var + 1e-5f);
    v0.x = (v0.x - mean) * rstd * ga.x + ba.x;
    v0.y = (v0.y - mean) * rstd * ga.y + ba.y;
    v0.z = (v0.z - mean) * rstd * ga.z + ba.z;
    v0.w = (v0.w - mean) * rstd * ga.w + ba.w;
    v1.x = (v1.x - mean) * rstd * gb.x + bb.x;
    v1.y = (v1.y - mean) * rstd * gb.y + bb.y;
    v1.z = (v1.z - mean) * rstd * gb.z + bb.z;
    v1.w = (v1.w - mean) * rstd * gb.w + bb.w;
    ((float4*)p)[0] = v0;
    ((float4*)p)[1] = v1;
  }
}

extern "C" void kernel_launch(void* const* d_in, const int* in_sizes, int n_in,
                              void* d_out, int out_size, void* d_ws,
                              size_t ws_size, hipStream_t stream) {
  const float* points = (const float*)d_in[0];
  const float* W_gate = (const float*)d_in[1];
  const float* b_gate = (const float*)d_in[2];
  const float* W_cand = (const float*)d_in[3];
  const float* b_cand = (const float*)d_in[4];
  const float* gamma = (const float*)d_in[5];
  const float* beta = (const float*)d_in[6];
  char* ws = (char*)d_ws;
  _Float16* Whpk = (_Float16*)(ws + OFF_WHPK);
  _Float16* Wxpk = (_Float16*)(ws + OFF_WXPK);
  _Float16* h_buf = (_Float16*)(ws + OFF_HBUF);
  unsigned* flags = (unsigned*)(ws + OFF_CNT);
  _Float16* rh_buf = (_Float16*)(ws + OFF_RH);
  _Float16* xgt = (_Float16*)(ws + OFF_XGT);
  float* out = (float*)d_out;

  // zero h0 + barrier flags (ws is re-poisoned before every timed launch)
  hipMemsetAsync(ws + OFF_HBUF, 0, 32768, stream);
  pack_kernel<<<768, 256, 0, stream>>>(W_gate, W_cand, Whpk, Wxpk);
  xgemm_kernel<<<S_LEN, TPB, 0, stream>>>(points, b_gate, b_cand, Wxpk, xgt);
  rec_kernel<<<NBLK, TPB, 0, stream>>>(Whpk, xgt, h_buf, rh_buf, flags, out);
  ln_kernel<<<512, 256, 0, stream>>>(out, gamma, beta);
}